// Round 2
// baseline (1004.814 us; speedup 1.0000x reference)
//
#include <hip/hip_runtime.h>

// out[bk] = sum_l max_m <ctx[bk,l,:], ent[bk,m,:]>,  B*K=1024, L=M=128, D=768, fp32.
// One workgroup per bk. fp32 -> bf16 on the fly, 16x16x32 bf16 MFMA.
// R2: LDS double-buffer (DC=32, 40 KB) + register prefetch of next chunk.
// Pipeline per chunk: barrier -> issue next chunk's global loads ->
// MFMA on current buffer (covers load latency) -> cvt+write other buffer.
// One barrier per chunk; no outstanding vmcnt at the barrier.

typedef __attribute__((ext_vector_type(8))) __bf16 bf16x8;
typedef __attribute__((ext_vector_type(4))) __bf16 bf16x4;
typedef __attribute__((ext_vector_type(4))) float f32x4;

#define L_DIM 128
#define D_DIM 768
#define DC    32               // D-chunk (one MFMA K-step)
#define NCH   (D_DIM / DC)     // 24
#define LDP   40               // padded LDS row (bf16): 32 + 8 -> 80 B rows

__global__ __launch_bounds__(256, 3)   // ~170 VGPR cap: no spill at ~125 live, 3 blocks/CU
void som_kernel(const float* __restrict__ context, float* __restrict__ out) {
    const int bk   = blockIdx.x;
    const int t    = threadIdx.x;
    const int lane = t & 63;
    const int wave = t >> 6;
    const int quad = (lane >> 4) & 3;
    const int l15  = lane & 15;

    const float* ctx_g = context + (size_t)bk * (2 * L_DIM * D_DIM);

    __shared__ __bf16 ctx_s[2][L_DIM * LDP];
    __shared__ __bf16 ent_s[2][L_DIM * LDP];
    __shared__ float wave_sum[4];

    // acc[rt][ct]: row = wave*32 + rt*16 + quad*4 + reg, col = ct*16 + (lane&15)
    f32x4 acc[2][8];
    const f32x4 zero = {0.f, 0.f, 0.f, 0.f};
#pragma unroll
    for (int rt = 0; rt < 2; ++rt)
#pragma unroll
        for (int ct = 0; ct < 8; ++ct)
            acc[rt][ct] = zero;

    // Staging geometry: per chunk, each array is 128 rows x 8 float4.
    // Thread t, iter i: row = (t>>3) + i*32, float4-col = t&7.
    const int row0 = t >> 3;
    const int c4   = t & 7;
    const float* gbase = ctx_g + (size_t)row0 * D_DIM + c4 * 4;

    float4 pc[4], pe[4];   // prefetch registers: 32 VGPRs

    auto load_regs = [&](int c) {
#pragma unroll
        for (int i = 0; i < 4; ++i) {
            const float* p = gbase + (size_t)i * 32 * D_DIM + c * DC;
            pc[i] = *(const float4*)p;
            pe[i] = *(const float4*)(p + L_DIM * D_DIM);
        }
    };
    auto cvt_write = [&](int b) {
#pragma unroll
        for (int i = 0; i < 4; ++i) {
            bf16x4 qc = {(__bf16)pc[i].x, (__bf16)pc[i].y, (__bf16)pc[i].z, (__bf16)pc[i].w};
            bf16x4 qe = {(__bf16)pe[i].x, (__bf16)pe[i].y, (__bf16)pe[i].z, (__bf16)pe[i].w};
            *(bf16x4*)&ctx_s[b][(row0 + i * 32) * LDP + c4 * 4] = qc;
            *(bf16x4*)&ent_s[b][(row0 + i * 32) * LDP + c4 * 4] = qe;
        }
    };

    // Prologue: stage chunk 0 into buffer 0.
    load_regs(0);
    cvt_write(0);

    int p = 0;
    for (int c = 0; c < NCH; ++c, p ^= 1) {
        __syncthreads();               // buf[p] staged by all waves; buf[p^1] free
        if (c + 1 < NCH) load_regs(c + 1);   // loads in flight during MFMA

        // MFMA on buf[p]: A frag A[m=lane&15][k=quad*8+j]; B frag same (C = A*B^T).
        const bf16x8 a0 = *(const bf16x8*)&ctx_s[p][(wave * 32 + l15) * LDP + quad * 8];
        const bf16x8 a1 = *(const bf16x8*)&ctx_s[p][(wave * 32 + 16 + l15) * LDP + quad * 8];
#pragma unroll
        for (int ct = 0; ct < 8; ++ct) {
            const bf16x8 b = *(const bf16x8*)&ent_s[p][(ct * 16 + l15) * LDP + quad * 8];
            acc[0][ct] = __builtin_amdgcn_mfma_f32_16x16x32_bf16(a0, b, acc[0][ct], 0, 0, 0);
            acc[1][ct] = __builtin_amdgcn_mfma_f32_16x16x32_bf16(a1, b, acc[1][ct], 0, 0, 0);
        }

        if (c + 1 < NCH) cvt_write(p ^ 1);   // consume vmcnt after MFMA issued
    }

    // Epilogue: row-max over 128 cols, then sum of maxes.
    // C/D layout: col = ct*16 + (lane&15), row = rt*16 + quad*4 + reg.
    float total = 0.f;
#pragma unroll
    for (int rt = 0; rt < 2; ++rt) {
#pragma unroll
        for (int reg = 0; reg < 4; ++reg) {
            float m = acc[rt][0][reg];
#pragma unroll
            for (int ct = 1; ct < 8; ++ct) m = fmaxf(m, acc[rt][ct][reg]);
            m = fmaxf(m, __shfl_xor(m, 1, 64));
            m = fmaxf(m, __shfl_xor(m, 2, 64));
            m = fmaxf(m, __shfl_xor(m, 4, 64));
            m = fmaxf(m, __shfl_xor(m, 8, 64));
            total += m;    // each quad-lane holds this row's max
        }
    }
    total += __shfl_xor(total, 16, 64);
    total += __shfl_xor(total, 32, 64);

    if (lane == 0) wave_sum[wave] = total;
    __syncthreads();
    if (t == 0)
        out[bk] = wave_sum[0] + wave_sum[1] + wave_sum[2] + wave_sum[3];
}

extern "C" void kernel_launch(void* const* d_in, const int* in_sizes, int n_in,
                              void* d_out, int out_size, void* d_ws, size_t ws_size,
                              hipStream_t stream) {
    const float* context = (const float*)d_in[0];
    float* out = (float*)d_out;
    som_kernel<<<dim3(1024), dim3(256), 0, stream>>>(context, out);
}

// Round 3
// 1002.837 us; speedup vs baseline: 1.0020x; 1.0020x over previous
//
#include <hip/hip_runtime.h>

// out[bk] = sum_l max_m <ctx[bk,l,:], ent[bk,m,:]>,  B*K=1024, L=M=128, D=768, fp32.
// One workgroup per bk. fp32 -> bf16 on the fly, 16x16x32 bf16 MFMA.
// R3: ctx (A operand) has no cross-wave reuse -> load it DIRECTLY from global
// into registers (cvt in regs), skip LDS entirely for it. Only ent (B operand,
// reused by all 4 waves) goes through a double-buffered bf16 LDS (20 KB).
// Halves LDS staging work and halves the bytes coupled to the per-chunk barrier.

typedef __attribute__((ext_vector_type(8))) __bf16 bf16x8;
typedef __attribute__((ext_vector_type(4))) __bf16 bf16x4;
typedef __attribute__((ext_vector_type(4))) float f32x4;

#define L_DIM 128
#define D_DIM 768
#define DC    32               // D-chunk (one MFMA K-step)
#define NCH   (D_DIM / DC)     // 24
#define LDP   40               // padded LDS row (bf16): 32 + 8 -> 80 B rows

__global__ __launch_bounds__(256, 3)
void som_kernel(const float* __restrict__ context, float* __restrict__ out) {
    const int bk   = blockIdx.x;
    const int t    = threadIdx.x;
    const int lane = t & 63;
    const int wave = t >> 6;
    const int quad = (lane >> 4) & 3;
    const int l15  = lane & 15;

    const float* ctx_g = context + (size_t)bk * (2 * L_DIM * D_DIM);
    const float* ent_g = ctx_g + (size_t)(L_DIM * D_DIM);

    __shared__ __bf16 ent_s[2][L_DIM * LDP];   // 2 x 10 KB
    __shared__ float wave_sum[4];

    // acc[rt][ct]: row = wave*32 + rt*16 + quad*4 + reg, col = ct*16 + (lane&15)
    f32x4 acc[2][8];
    const f32x4 zero = {0.f, 0.f, 0.f, 0.f};
#pragma unroll
    for (int rt = 0; rt < 2; ++rt)
#pragma unroll
        for (int ct = 0; ct < 8; ++ct)
            acc[rt][ct] = zero;

    // ---- ent staging geometry: 128 rows x 8 float4 per chunk, 4 per thread ----
    const int row0 = t >> 3;          // 0..31
    const int c4   = t & 7;
    const float* ent_base = ent_g + (size_t)row0 * D_DIM + c4 * 4;

    // ---- A geometry: wave's rows wave*32 + l15 and +16, cols quad*8..+7 ----
    const float* a_base0 = ctx_g + (size_t)(wave * 32 + l15) * D_DIM + quad * 8;
    const float* a_base1 = a_base0 + (size_t)16 * D_DIM;

    float4 pe[4];         // ent prefetch (16 regs)
    float4 pa[4];         // A prefetch: row0 lo/hi, row1 lo/hi (16 regs)
    bf16x8 a_cur0, a_cur1;

    auto load_ent = [&](int c) {
#pragma unroll
        for (int i = 0; i < 4; ++i)
            pe[i] = *(const float4*)(ent_base + (size_t)i * 32 * D_DIM + c * DC);
    };
    auto write_ent = [&](int b) {
#pragma unroll
        for (int i = 0; i < 4; ++i) {
            bf16x4 q = {(__bf16)pe[i].x, (__bf16)pe[i].y, (__bf16)pe[i].z, (__bf16)pe[i].w};
            *(bf16x4*)&ent_s[b][(row0 + i * 32) * LDP + c4 * 4] = q;
        }
    };
    auto load_a = [&](int c) {
        pa[0] = *(const float4*)(a_base0 + c * DC);
        pa[1] = *(const float4*)(a_base0 + c * DC + 4);
        pa[2] = *(const float4*)(a_base1 + c * DC);
        pa[3] = *(const float4*)(a_base1 + c * DC + 4);
    };
    auto cvt_a = [&]() {
        a_cur0 = bf16x8{(__bf16)pa[0].x, (__bf16)pa[0].y, (__bf16)pa[0].z, (__bf16)pa[0].w,
                        (__bf16)pa[1].x, (__bf16)pa[1].y, (__bf16)pa[1].z, (__bf16)pa[1].w};
        a_cur1 = bf16x8{(__bf16)pa[2].x, (__bf16)pa[2].y, (__bf16)pa[2].z, (__bf16)pa[2].w,
                        (__bf16)pa[3].x, (__bf16)pa[3].y, (__bf16)pa[3].z, (__bf16)pa[3].w};
    };

    // Prologue: stage chunk 0.
    load_ent(0);
    load_a(0);
    write_ent(0);
    cvt_a();

    int p = 0;
    for (int c = 0; c < NCH; ++c, p ^= 1) {
        __syncthreads();                       // ent buf p staged by all waves
        if (c + 1 < NCH) { load_ent(c + 1); load_a(c + 1); }   // in flight over MFMA

        // MFMA on (a_cur, ent_s[p]). B frag: B[n=lane&15][k=quad*8+j] (C = A*B^T).
#pragma unroll
        for (int ct = 0; ct < 8; ++ct) {
            const bf16x8 b = *(const bf16x8*)&ent_s[p][(ct * 16 + l15) * LDP + quad * 8];
            acc[0][ct] = __builtin_amdgcn_mfma_f32_16x16x32_bf16(a_cur0, b, acc[0][ct], 0, 0, 0);
            acc[1][ct] = __builtin_amdgcn_mfma_f32_16x16x32_bf16(a_cur1, b, acc[1][ct], 0, 0, 0);
        }

        if (c + 1 < NCH) { cvt_a(); write_ent(p ^ 1); }  // consume loads post-MFMA
    }

    // Epilogue: row-max over 128 cols, then sum of maxes.
    // C/D layout: col = ct*16 + (lane&15), row = rt*16 + quad*4 + reg.
    float total = 0.f;
#pragma unroll
    for (int rt = 0; rt < 2; ++rt) {
#pragma unroll
        for (int reg = 0; reg < 4; ++reg) {
            float m = acc[rt][0][reg];
#pragma unroll
            for (int ct = 1; ct < 8; ++ct) m = fmaxf(m, acc[rt][ct][reg]);
            m = fmaxf(m, __shfl_xor(m, 1, 64));
            m = fmaxf(m, __shfl_xor(m, 2, 64));
            m = fmaxf(m, __shfl_xor(m, 4, 64));
            m = fmaxf(m, __shfl_xor(m, 8, 64));
            total += m;    // each quad-lane holds this row's max
        }
    }
    total += __shfl_xor(total, 16, 64);
    total += __shfl_xor(total, 32, 64);

    if (lane == 0) wave_sum[wave] = total;
    __syncthreads();
    if (t == 0)
        out[bk] = wave_sum[0] + wave_sum[1] + wave_sum[2] + wave_sum[3];
}

extern "C" void kernel_launch(void* const* d_in, const int* in_sizes, int n_in,
                              void* d_out, int out_size, void* d_ws, size_t ws_size,
                              hipStream_t stream) {
    const float* context = (const float*)d_in[0];
    float* out = (float*)d_out;
    som_kernel<<<dim3(1024), dim3(256), 0, stream>>>(context, out);
}